// Round 24
// baseline (207.218 us; speedup 1.0000x reference)
//
#include <hip/hip_runtime.h>
#include <hip/hip_bf16.h>
#include <cstdint>

#define BATCH 32
#define CIN   256
#define COUT  256
#define HW    56
#define NEXP  8
#define HP    58

typedef __bf16 bf16x8 __attribute__((ext_vector_type(8)));
typedef float  f32x4  __attribute__((ext_vector_type(4)));
typedef unsigned short u16x8 __attribute__((ext_vector_type(8)));

static __device__ __forceinline__ unsigned short f32_to_bf16(float f) {
    uint32_t u = __builtin_bit_cast(uint32_t, f);
    return (unsigned short)((u + 0x7FFFu + ((u >> 16) & 1u)) >> 16);
}

// ---- x fp32 [b][i][56][56] -> xTp bf16 [b][58][58][i] (zero halo) + GAP row-sums ----
// Vectorized stores: 2 channels per lane -> one u32 store.
__global__ void transpose_kernel(const float* __restrict__ x, unsigned short* __restrict__ xtp,
                                 float* __restrict__ gap) {
    int hp = blockIdx.x;
    int ib = blockIdx.y;
    int b  = blockIdx.z;
    int t  = threadIdx.x;
    __shared__ float tile[32][57];
    bool in_h = (hp >= 1 && hp <= HW);
    if (in_h) {
        const float* src = x + (((size_t)b * CIN + ib * 32) * HW + (hp - 1)) * HW;
        for (int idx = t; idx < 32 * HW; idx += 256) {
            int il = idx / HW, w = idx - il * HW;
            tile[il][w] = src[(size_t)il * (HW * HW) + w];
        }
    }
    __syncthreads();
    unsigned short* dst = xtp + (((size_t)b * HP + hp) * HP) * CIN + ib * 32;
    for (int idx = t; idx < HP * 16; idx += 256) {
        int wp = idx >> 4, il2 = (idx & 15) * 2;
        unsigned short v0 = 0, v1 = 0;
        if (in_h && wp >= 1 && wp <= HW) {
            v0 = f32_to_bf16(tile[il2][wp - 1]);
            v1 = f32_to_bf16(tile[il2 + 1][wp - 1]);
        }
        *reinterpret_cast<uint32_t*>(&dst[(size_t)wp * CIN + il2]) =
            (uint32_t)v0 | ((uint32_t)v1 << 16);
    }
    if (in_h) {
        int c = t >> 3, j0 = t & 7;
        float s = 0.f;
        for (int j = j0; j < HW; j += 8) s += tile[c][j];
        s += __shfl_down(s, 4, 8);
        s += __shfl_down(s, 2, 8);
        s += __shfl_down(s, 1, 8);
        if (j0 == 0) atomicAdd(&gap[b * CIN + ib * 32 + c], s);
    }
}

// ---- cmb pages: [b][ib][r] of 8192 elems = [o(256)][k(32)] row-major ----
// Grid (COUT, 4): 8 batches per block. ROUTING FUSED at head (threads 0-63).
__global__ void combine_kernel(const float* __restrict__ kw, const float* __restrict__ gap,
                               const float* __restrict__ fcw, const float* __restrict__ fcb,
                               unsigned short* __restrict__ cmb) {
    int o  = blockIdx.x;
    int bq = blockIdx.y;             // batch quarter
    int t  = threadIdx.x;            // channel i
    __shared__ float rs[8][NEXP];
    __shared__ __align__(16) unsigned short sbuf[8][9][32];
    float kv[NEXP][9];
    #pragma unroll
    for (int e = 0; e < NEXP; ++e) {
        const float* p = kw + (((size_t)e * COUT + o) * CIN + t) * 9;
        #pragma unroll
        for (int r = 0; r < 9; ++r) kv[e][r] = p[r];
    }
    if (t < 64) {
        int bb = t >> 3, e = t & 7;
        const float* g = gap + (bq * 8 + bb) * CIN;
        const float* w = fcw + e * CIN;
        float z = 0.f;
        #pragma unroll 4
        for (int c = 0; c < CIN; ++c) z += g[c] * w[c];
        z = z * (1.0f / 3136.0f) + fcb[e];
        rs[bb][e] = 1.f / (1.f + expf(-z));
    }
    __syncthreads();
    int ib = t >> 5, il = t & 31;
    for (int bb = 0; bb < 8; ++bb) {
        int b = bq * 8 + bb;
        #pragma unroll
        for (int r = 0; r < 9; ++r) {
            float s = 0.f;
            #pragma unroll
            for (int e = 0; e < NEXP; ++e) s += rs[bb][e] * kv[e][r];
            sbuf[ib][r][il] = f32_to_bf16(s);
        }
        __syncthreads();
        for (int sid = t; sid < 288; sid += 256) {
            int ib2 = sid / 36, rem = sid % 36;
            int rr = rem >> 2, slot = rem & 3;
            size_t dst = (size_t)(b * 72 + ib2 * 9 + rr) * 8192 + o * 32 + slot * 8;
            *reinterpret_cast<u16x8*>(cmb + dst) =
                *reinterpret_cast<const u16x8*>(&sbuf[ib2][rr][slot * 8]);
        }
        __syncthreads();
    }
}

// ---- conv: 256 thr = 4 waves (64o x 112px each, acc[4][7], 16x16x32 MFMA).
// Block = 256o x 112px (14h x 8w); 896 blocks; 40KB LDS dbuf -> 2 blocks/CU desynced.
// A: af/afn register double-buffer (loads for s+1 before the s cluster).
// B: bv/bvn register double-buffer — ds_reads for r+1 issued BEFORE the r cluster,
//    so the cluster consumes LDS data loaded one step earlier (no lgkm stall at the
//    cluster head except once per ib). Window 160 pos x 128B swizzled rows.
// ~124 VGPR + 112 AGPR = 236 <= 256 @ (256,2): no spill.
// Sync: raw s_barrier + counted vmcnt(4) per ib.
#define WBUF 20480

__global__ __launch_bounds__(256, 2)
void conv_kernel(const unsigned short* __restrict__ xtp, const unsigned short* __restrict__ cmb,
                 float* __restrict__ out) {
    __shared__ __align__(16) char lds[2 * WBUF];
    const int t = threadIdx.x, wave = t >> 6, l = t & 63;
    const int lr = l & 15, lk = l >> 4;

    // bijective XCD swizzle: 896 = 8 x 112
    int bid = blockIdx.x;
    int wg  = (bid & 7) * 112 + (bid >> 3);
    int b   = wg / 28, pt = wg - b * 28;
    int ty = pt / 7, tx = pt - ty * 7;
    int oh0 = ty * 14, ow0 = tx * 8;

    const unsigned short* xb = xtp + (size_t)b * (HP * HP * CIN);

    // staging: 1280 chunks of 16B (160 pos x 8 slots); chunk c: pos=c>>3, slot=c&7,
    // source chunk q = (slot ^ (pos&7)) & 3 (junk slots dup a valid chunk)
    int ws[5];
    #pragma unroll
    for (int k = 0; k < 5; ++k) {
        int c = (wave + 4 * k) * 64 + l;
        int pos = c >> 3, slot = c & 7;
        int q = (slot ^ (pos & 7)) & 3;
        int hh = pos / 10, ww = pos - hh * 10;
        ws[k] = ((oh0 + hh) * HP + (ow0 + ww)) * CIN + q * 8;
    }

    // A: uniform page base (SGPR) + per-lane 32-bit offset
    const char* cmbB = (const char*)cmb + (size_t)b * (72 * 16384);
    const int laneoff = wave * 4096 + lr * 64 + lk * 16;   // bytes within a 16KB page

#define STAGE_W(ibx, buf)                                                                   \
    { _Pragma("unroll")                                                                     \
      for (int k = 0; k < 5; ++k)                                                           \
          __builtin_amdgcn_global_load_lds(                                                 \
              (const __attribute__((address_space(1))) void*)(xb + ws[k] + (ibx) * 32),     \
              (__attribute__((address_space(3))) void*)(lds + (buf) + (wave + 4 * k) * 1024), \
              16, 0, 0); }

#define LOAD_BV(dst, base, rr)                                                              \
    { const int dh_ = (rr) / 3, dw_ = (rr) - dh_ * 3;                                       \
      const int pb_ = laneterm + dh_ * 10 + dw_;                                            \
      _Pragma("unroll")                                                                     \
      for (int nt = 0; nt < 7; ++nt) {                                                      \
          int pos_ = pb_ + nt * 20;                                                         \
          dst[nt] = *reinterpret_cast<const bf16x8*>(                                       \
              (base) + pos_ * 128 + ((lk ^ (pos_ & 7)) << 4));                              \
      } }

    f32x4 acc[4][7];
    #pragma unroll
    for (int m = 0; m < 4; ++m)
        #pragma unroll
        for (int nt = 0; nt < 7; ++nt) acc[m][nt] = (f32x4){0.f, 0.f, 0.f, 0.f};

    const int laneterm = (lr >> 3) * 10 + (lr & 7);

    // prologue: window ib=0 staged; A page 0 issued (newest); counted drain; barrier
    STAGE_W(0, 0);
    u16x8 af[4];
    #pragma unroll
    for (int m = 0; m < 4; ++m)
        af[m] = *reinterpret_cast<const u16x8*>(cmbB + laneoff + m * 1024);
    asm volatile("s_waitcnt vmcnt(4)" ::: "memory");   // staging (older) drained; af in flight
    __builtin_amdgcn_s_barrier();

    for (int ib = 0; ib < 8; ++ib) {
        if (ib < 7) STAGE_W(ib + 1, ((ib + 1) & 1) * WBUF);
        const char* curw = lds + (ib & 1) * WBUF;
        // prime bv for r=0 of this ib (one cold lgkm wait per ib, amortized 1/9)
        bf16x8 bv[7];
        LOAD_BV(bv, curw, 0);
        #pragma unroll 1
        for (int r = 0; r < 9; ++r) {
            const int s = ib * 9 + r;
            // prefetch A for next K-step (L2 latency hides under this cluster)
            u16x8 afn[4];
            if (s < 71) {
                const char* pb = cmbB + (size_t)(s + 1) * 16384;
                #pragma unroll
                for (int m = 0; m < 4; ++m)
                    afn[m] = *reinterpret_cast<const u16x8*>(pb + laneoff + m * 1024);
            }
            // prefetch B for next r-step (LDS latency hides under this cluster)
            bf16x8 bvn[7];
            if (r < 8) LOAD_BV(bvn, curw, r + 1);
            __builtin_amdgcn_s_setprio(1);
            #pragma unroll
            for (int nt = 0; nt < 7; ++nt)
                #pragma unroll
                for (int m = 0; m < 4; ++m)
                    acc[m][nt] = __builtin_amdgcn_mfma_f32_16x16x32_bf16(
                        __builtin_bit_cast(bf16x8, af[m]), bv[nt], acc[m][nt], 0, 0, 0);
            __builtin_amdgcn_s_setprio(0);
            if (s < 71) {
                #pragma unroll
                for (int m = 0; m < 4; ++m) af[m] = afn[m];
            }
            if (r < 8) {
                #pragma unroll
                for (int nt = 0; nt < 7; ++nt) bv[nt] = bvn[nt];
            }
        }
        if (ib < 7) {
            // keep next ib's af in flight; staging (older) fully retired by now
            asm volatile("s_waitcnt vmcnt(4)" ::: "memory");
            __builtin_amdgcn_s_barrier();
        }
    }

    // epilogue: D col = lane&15 (px), row = lk*4 + reg (o)
    #pragma unroll
    for (int m = 0; m < 4; ++m)
        #pragma unroll
        for (int nt = 0; nt < 7; ++nt) {
            int oh = oh0 + nt * 2 + (lr >> 3), ow = ow0 + (lr & 7);
            #pragma unroll
            for (int reg = 0; reg < 4; ++reg) {
                int o = wave * 64 + m * 16 + lk * 4 + reg;
                out[(((size_t)b * COUT + o) * HW + oh) * HW + ow] = acc[m][nt][reg];
            }
        }
#undef STAGE_W
#undef LOAD_BV
}

extern "C" void kernel_launch(void* const* d_in, const int* in_sizes, int n_in,
                              void* d_out, int out_size, void* d_ws, size_t ws_size,
                              hipStream_t stream) {
    const float* x   = (const float*)d_in[0];
    const float* kw  = (const float*)d_in[1];
    const float* fcw = (const float*)d_in[2];
    const float* fcb = (const float*)d_in[3];
    float* out = (float*)d_out;

    char* ws = (char*)d_ws;
    float* gap  = (float*)(ws + 0);                        //  32768 B
    unsigned short* cmb = (unsigned short*)(ws + 33792);   // 37748736 B
    unsigned short* xtp = (unsigned short*)(ws + 33792 + 37748736); // 55107584 B

    hipMemsetAsync(gap, 0, BATCH * CIN * sizeof(float), stream);
    transpose_kernel<<<dim3(HP, 8, BATCH), 256, 0, stream>>>(x, xtp, gap);
    combine_kernel<<<dim3(COUT, 4), 256, 0, stream>>>(kw, gap, fcw, fcb, cmb);
    conv_kernel<<<dim3(896), 256, 0, stream>>>(xtp, cmb, out);
}

// Round 25
// 200.960 us; speedup vs baseline: 1.0311x; 1.0311x over previous
//
#include <hip/hip_runtime.h>
#include <hip/hip_bf16.h>
#include <cstdint>

#define BATCH 32
#define CIN   256
#define COUT  256
#define HW    56
#define NEXP  8
#define HP    58

typedef __bf16 bf16x8 __attribute__((ext_vector_type(8)));
typedef float  f32x4  __attribute__((ext_vector_type(4)));
typedef unsigned short u16x8 __attribute__((ext_vector_type(8)));

static __device__ __forceinline__ unsigned short f32_to_bf16(float f) {
    uint32_t u = __builtin_bit_cast(uint32_t, f);
    return (unsigned short)((u + 0x7FFFu + ((u >> 16) & 1u)) >> 16);
}

// ---- x fp32 [b][i][56][56] -> xTp bf16 [b][58][58][i] (zero halo) + GAP row-sums ----
// Vectorized stores: 2 channels per lane -> one u32 store.
__global__ void transpose_kernel(const float* __restrict__ x, unsigned short* __restrict__ xtp,
                                 float* __restrict__ gap) {
    int hp = blockIdx.x;
    int ib = blockIdx.y;
    int b  = blockIdx.z;
    int t  = threadIdx.x;
    __shared__ float tile[32][57];
    bool in_h = (hp >= 1 && hp <= HW);
    if (in_h) {
        const float* src = x + (((size_t)b * CIN + ib * 32) * HW + (hp - 1)) * HW;
        for (int idx = t; idx < 32 * HW; idx += 256) {
            int il = idx / HW, w = idx - il * HW;
            tile[il][w] = src[(size_t)il * (HW * HW) + w];
        }
    }
    __syncthreads();
    unsigned short* dst = xtp + (((size_t)b * HP + hp) * HP) * CIN + ib * 32;
    for (int idx = t; idx < HP * 16; idx += 256) {
        int wp = idx >> 4, il2 = (idx & 15) * 2;
        unsigned short v0 = 0, v1 = 0;
        if (in_h && wp >= 1 && wp <= HW) {
            v0 = f32_to_bf16(tile[il2][wp - 1]);
            v1 = f32_to_bf16(tile[il2 + 1][wp - 1]);
        }
        *reinterpret_cast<uint32_t*>(&dst[(size_t)wp * CIN + il2]) =
            (uint32_t)v0 | ((uint32_t)v1 << 16);
    }
    if (in_h) {
        int c = t >> 3, j0 = t & 7;
        float s = 0.f;
        for (int j = j0; j < HW; j += 8) s += tile[c][j];
        s += __shfl_down(s, 4, 8);
        s += __shfl_down(s, 2, 8);
        s += __shfl_down(s, 1, 8);
        if (j0 == 0) atomicAdd(&gap[b * CIN + ib * 32 + c], s);
    }
}

// ---- cmb pages: [b][ib][r] of 8192 elems = [o(256)][k(32)] row-major ----
// Grid (COUT, 4): 8 batches per block (measured best). ROUTING FUSED at head:
// threads 0-63 each compute one (bb,e) sigmoid-dot, overlapped with the kv loads.
__global__ void combine_kernel(const float* __restrict__ kw, const float* __restrict__ gap,
                               const float* __restrict__ fcw, const float* __restrict__ fcb,
                               unsigned short* __restrict__ cmb) {
    int o  = blockIdx.x;
    int bq = blockIdx.y;             // batch quarter
    int t  = threadIdx.x;            // channel i
    __shared__ float rs[8][NEXP];
    __shared__ __align__(16) unsigned short sbuf[8][9][32];
    // kv loads issued first so their latency overlaps the routing dot below
    float kv[NEXP][9];
    #pragma unroll
    for (int e = 0; e < NEXP; ++e) {
        const float* p = kw + (((size_t)e * COUT + o) * CIN + t) * 9;
        #pragma unroll
        for (int r = 0; r < 9; ++r) kv[e][r] = p[r];
    }
    if (t < 64) {
        int bb = t >> 3, e = t & 7;
        const float* g = gap + (bq * 8 + bb) * CIN;
        const float* w = fcw + e * CIN;
        float z = 0.f;
        #pragma unroll 4
        for (int c = 0; c < CIN; ++c) z += g[c] * w[c];
        z = z * (1.0f / 3136.0f) + fcb[e];
        rs[bb][e] = 1.f / (1.f + expf(-z));
    }
    __syncthreads();
    int ib = t >> 5, il = t & 31;
    for (int bb = 0; bb < 8; ++bb) {
        int b = bq * 8 + bb;
        #pragma unroll
        for (int r = 0; r < 9; ++r) {
            float s = 0.f;
            #pragma unroll
            for (int e = 0; e < NEXP; ++e) s += rs[bb][e] * kv[e][r];
            sbuf[ib][r][il] = f32_to_bf16(s);
        }
        __syncthreads();
        // 288 vector stores of 16B: sid -> (ib2, r, slot)
        for (int sid = t; sid < 288; sid += 256) {
            int ib2 = sid / 36, rem = sid % 36;
            int rr = rem >> 2, slot = rem & 3;
            size_t dst = (size_t)(b * 72 + ib2 * 9 + rr) * 8192 + o * 32 + slot * 8;
            *reinterpret_cast<u16x8*>(cmb + dst) =
                *reinterpret_cast<const u16x8*>(&sbuf[ib2][rr][slot * 8]);
        }
        __syncthreads();
    }
}

// ---- conv: 256 thr = 4 waves (64o x 112px each, acc[4][7], 16x16x32 MFMA).
// Block = 256o x 112px (14h x 8w); 896 blocks; 40KB LDS dbuf -> 2 blocks/CU,
// mutually DESYNCED (no shared barrier).
// A: af/afn register double-buffer, loads for s+1 issued BEFORE the s cluster;
//    SGPR page base + 1 VGPR lane offset.
// B: window 160 pos x 128B (8 slots of 16B), chunk q at slot q^(pos&7) via
//    inverse-swizzled global_load_lds SOURCE; read slot = lk^(pos&7).
// r-loop unroll 1 keeps VGPR ~96; 96 + 112 AGPR = 208 <= 256 @ (256,2): no spill.
// Sync: raw s_barrier + counted vmcnt(4) per ib.
#define WBUF 20480

__global__ __launch_bounds__(256, 2)
void conv_kernel(const unsigned short* __restrict__ xtp, const unsigned short* __restrict__ cmb,
                 float* __restrict__ out) {
    __shared__ __align__(16) char lds[2 * WBUF];
    const int t = threadIdx.x, wave = t >> 6, l = t & 63;
    const int lr = l & 15, lk = l >> 4;

    // bijective XCD swizzle: 896 = 8 x 112
    int bid = blockIdx.x;
    int wg  = (bid & 7) * 112 + (bid >> 3);
    int b   = wg / 28, pt = wg - b * 28;
    int ty = pt / 7, tx = pt - ty * 7;
    int oh0 = ty * 14, ow0 = tx * 8;

    const unsigned short* xb = xtp + (size_t)b * (HP * HP * CIN);

    // staging: 1280 chunks of 16B (160 pos x 8 slots); chunk c: pos=c>>3, slot=c&7,
    // source chunk q = (slot ^ (pos&7)) & 3 (junk slots dup a valid chunk)
    int ws[5];
    #pragma unroll
    for (int k = 0; k < 5; ++k) {
        int c = (wave + 4 * k) * 64 + l;
        int pos = c >> 3, slot = c & 7;
        int q = (slot ^ (pos & 7)) & 3;
        int hh = pos / 10, ww = pos - hh * 10;
        ws[k] = ((oh0 + hh) * HP + (ow0 + ww)) * CIN + q * 8;
    }

    // A: uniform page base (SGPR) + per-lane 32-bit offset
    const char* cmbB = (const char*)cmb + (size_t)b * (72 * 16384);
    const int laneoff = wave * 4096 + lr * 64 + lk * 16;   // bytes within a 16KB page

#define STAGE_W(ibx, buf)                                                                   \
    { _Pragma("unroll")                                                                     \
      for (int k = 0; k < 5; ++k)                                                           \
          __builtin_amdgcn_global_load_lds(                                                 \
              (const __attribute__((address_space(1))) void*)(xb + ws[k] + (ibx) * 32),     \
              (__attribute__((address_space(3))) void*)(lds + (buf) + (wave + 4 * k) * 1024), \
              16, 0, 0); }

    f32x4 acc[4][7];
    #pragma unroll
    for (int m = 0; m < 4; ++m)
        #pragma unroll
        for (int nt = 0; nt < 7; ++nt) acc[m][nt] = (f32x4){0.f, 0.f, 0.f, 0.f};

    const int laneterm = (lr >> 3) * 10 + (lr & 7);

    // prologue: window ib=0 staged; A page 0 issued (newest); counted drain; barrier
    STAGE_W(0, 0);
    u16x8 af[4];
    #pragma unroll
    for (int m = 0; m < 4; ++m)
        af[m] = *reinterpret_cast<const u16x8*>(cmbB + laneoff + m * 1024);
    asm volatile("s_waitcnt vmcnt(4)" ::: "memory");   // staging (older) drained; af in flight
    __builtin_amdgcn_s_barrier();

    for (int ib = 0; ib < 8; ++ib) {
        if (ib < 7) STAGE_W(ib + 1, ((ib + 1) & 1) * WBUF);
        const char* curw = lds + (ib & 1) * WBUF;
        #pragma unroll 1
        for (int r = 0; r < 9; ++r) {
            const int s = ib * 9 + r;
            const int dh = r / 3, dw = r - dh * 3;
            const int posbase = laneterm + dh * 10 + dw;
            // issue next K-step's A loads BEFORE the cluster: latency hides under MFMAs
            u16x8 afn[4];
            if (s < 71) {
                const char* pb = cmbB + (size_t)(s + 1) * 16384;
                #pragma unroll
                for (int m = 0; m < 4; ++m)
                    afn[m] = *reinterpret_cast<const u16x8*>(pb + laneoff + m * 1024);
            }
            __builtin_amdgcn_s_setprio(1);
            #pragma unroll
            for (int nt = 0; nt < 7; ++nt) {
                int pos = posbase + nt * 20;
                bf16x8 bv = *reinterpret_cast<const bf16x8*>(
                    curw + pos * 128 + ((lk ^ (pos & 7)) << 4));
                #pragma unroll
                for (int m = 0; m < 4; ++m)
                    acc[m][nt] = __builtin_amdgcn_mfma_f32_16x16x32_bf16(
                        __builtin_bit_cast(bf16x8, af[m]), bv, acc[m][nt], 0, 0, 0);
            }
            __builtin_amdgcn_s_setprio(0);
            if (s < 71) {
                #pragma unroll
                for (int m = 0; m < 4; ++m) af[m] = afn[m];   // compiler-counted vmcnt wait
            }
        }
        if (ib < 7) {
            // keep next ib's af in flight; staging (older) fully retired by now
            asm volatile("s_waitcnt vmcnt(4)" ::: "memory");
            __builtin_amdgcn_s_barrier();
        }
    }

    // epilogue: D col = lane&15 (px), row = lk*4 + reg (o)
    #pragma unroll
    for (int m = 0; m < 4; ++m)
        #pragma unroll
        for (int nt = 0; nt < 7; ++nt) {
            int oh = oh0 + nt * 2 + (lr >> 3), ow = ow0 + (lr & 7);
            #pragma unroll
            for (int reg = 0; reg < 4; ++reg) {
                int o = wave * 64 + m * 16 + lk * 4 + reg;
                out[(((size_t)b * COUT + o) * HW + oh) * HW + ow] = acc[m][nt][reg];
            }
        }
#undef STAGE_W
}

extern "C" void kernel_launch(void* const* d_in, const int* in_sizes, int n_in,
                              void* d_out, int out_size, void* d_ws, size_t ws_size,
                              hipStream_t stream) {
    const float* x   = (const float*)d_in[0];
    const float* kw  = (const float*)d_in[1];
    const float* fcw = (const float*)d_in[2];
    const float* fcb = (const float*)d_in[3];
    float* out = (float*)d_out;

    char* ws = (char*)d_ws;
    float* gap  = (float*)(ws + 0);                        //  32768 B
    unsigned short* cmb = (unsigned short*)(ws + 33792);   // 37748736 B
    unsigned short* xtp = (unsigned short*)(ws + 33792 + 37748736); // 55107584 B

    hipMemsetAsync(gap, 0, BATCH * CIN * sizeof(float), stream);
    transpose_kernel<<<dim3(HP, 8, BATCH), 256, 0, stream>>>(x, xtp, gap);
    combine_kernel<<<dim3(COUT, 4), 256, 0, stream>>>(kw, gap, fcw, fcb, cmb);
    conv_kernel<<<dim3(896), 256, 0, stream>>>(xtp, cmb, out);
}